// Round 5
// baseline (210.453 us; speedup 1.0000x reference)
//
#include <hip/hip_runtime.h>
#include <hip/hip_bf16.h>
#include <hip/hip_cooperative_groups.h>
#include <math.h>

namespace cg = cooperative_groups;

#define BB 8
#define BS 65536  // 256*256

typedef __attribute__((ext_vector_type(8))) short short8v;
typedef __attribute__((ext_vector_type(4))) float f32x4;
typedef unsigned short u16;
typedef __attribute__((address_space(1))) const void gv_t;
typedef __attribute__((address_space(3))) void lv_t;

__device__ __forceinline__ u16 f2bf(float v) {
  __hip_bfloat16 h = __float2bfloat16(v);
  return *reinterpret_cast<u16*>(&h);
}

// LDS tile [ROWS][64] bf16, row = 128 B = 8 chunks of 16 B. XOR swizzle
// cs = c ^ (r&7) applied on the GLOBAL SOURCE (gload_lds writes linearly)
// and identically on the frag read / ds-write side (rule #21).
template <int ITERS>
__device__ __forceinline__ void stage_g(const u16* __restrict__ g, int row0,
                                        int stride, int k0, u16* lds, int tid) {
#pragma unroll
  for (int it = 0; it < ITERS; ++it) {
    int slot = it * 256 + tid;
    int r = slot >> 3, c = slot & 7;
    int cs = c ^ (r & 7);
    const u16* src = g + (size_t)(row0 + r) * stride + k0 + cs * 8;
    u16* dst = lds + (size_t)(it * 256 + (tid & ~63)) * 8;
    __builtin_amdgcn_global_load_lds((gv_t*)src, (lv_t*)dst, 16, 0, 0);
  }
}

__device__ __forceinline__ short8v frag(const u16* lds, int rb, int sk,
                                        int lane) {
  int r = rb * 16 + (lane & 15);
  int c = sk * 4 + (lane >> 4);
  int cs = c ^ (r & 7);
  return *(const short8v*)(lds + r * 64 + cs * 8);
}

// ---------------------------------------------------------------------------
// One cooperative kernel, grid 512 x 256 (2 blocks/CU, 8 waves/CU).
// P : xt = bf16(x^T), Wh = bf16(W), c2m/sgn consts          (137 blocks)
// S1: L2p[n][dd] = c2m*(xt.W1^T + b_lin); R2t[dd][n] = c2m*(W2.xt^T)
//     64x32 MFMA tiles, (32 L + 32 R) x 8b = 512 blocks
// S2: e = 1.5*sum sgn*R + bias + sum sgn*|L+R|, mask, softmax -> attn bf16
//     4 rows/block x 64 x 8b = 512 blocks
// S3: out = sigmoid(x.attn^T) + x, 32x32 MFMA tiles, 64 x 8b = 512 blocks
// ---------------------------------------------------------------------------
__global__ __launch_bounds__(256) void gat_mega(
    const float* __restrict__ x, const int* __restrict__ adj,
    const float* __restrict__ W, const float* __restrict__ b_lin,
    const float* __restrict__ a, const float* __restrict__ bias,
    float* __restrict__ out, float* __restrict__ L2p,
    float* __restrict__ R2t, u16* __restrict__ xt, u16* __restrict__ Wh,
    u16* __restrict__ attnh, float* __restrict__ c2m,
    float* __restrict__ sgn) {
  cg::grid_group grid = cg::this_grid();
  __shared__ __align__(16) char smem_raw[64 * 65 * 4];  // 16640 B, re-used
  __shared__ float redm[4][4], reds[4][4];
  const int bk = blockIdx.x, tid = threadIdx.x;
  const int lane = tid & 63, wid = tid >> 6;

  // ---------------- Stage P ----------------
  if (bk < 128) {
    float(*tile)[65] = (float(*)[65])smem_raw;
    const int b = bk >> 4, t2 = bk & 15;
    const int f0 = (t2 & 3) * 64, n0 = (t2 >> 2) * 64;
    const float* xb = x + (size_t)b * BS;
#pragma unroll
    for (int it = 0; it < 16; ++it) {
      int idx = it * 256 + tid;
      int r = idx >> 6, c = idx & 63;
      tile[r][c] = xb[(f0 + r) * 256 + n0 + c];
    }
    __syncthreads();
#pragma unroll
    for (int it = 0; it < 16; ++it) {
      int idx = it * 256 + tid;
      int rr = idx >> 6, cc = idx & 63;
      xt[(size_t)b * BS + (n0 + rr) * 256 + f0 + cc] = f2bf(tile[cc][rr]);
    }
  } else if (bk < 136) {
    const int base = (bk - 128) * 16384;
#pragma unroll
    for (int it = 0; it < 16; ++it) {
      int i = base + (it * 256 + tid) * 4;
      float4 v = *(const float4*)(W + i);
      u16 o[4] = {f2bf(v.x), f2bf(v.y), f2bf(v.z), f2bf(v.w)};
      *(uint2*)(Wh + i) = *(const uint2*)o;
    }
  } else if (bk == 136) {
    float av = a[tid];
    c2m[tid] = fabsf(0.4f * av);
    sgn[tid] = (av >= 0.f) ? 1.f : -1.f;
  }
  grid.sync();

  // ---------------- Stage 1: projection GEMMs ----------------
  {
    u16* At = (u16*)smem_raw;            // 64x64
    u16* Bt = (u16*)(smem_raw + 8192);   // 32x64
    const int b = bk >> 6, tt = bk & 63;
    const bool isR = tt >= 32;
    const int t2 = tt & 31;
    const int mblk = (t2 >> 3) * 64, nblk = (t2 & 7) * 32;
    const int wr = (wid >> 1) * 32, wc = (wid & 1) * 16;

    const u16 *Ab, *Bb;
    int as_, bs_, ak;
    if (!isR) {
      Ab = xt + (size_t)b * BS; as_ = 256; ak = 0;  // A rows = n, k = f
      Bb = Wh; bs_ = 512;                           // B rows = dd (W1)
    } else {
      Ab = Wh; as_ = 512; ak = 256;                 // A rows = dd (W2)
      Bb = xt + (size_t)b * BS; bs_ = 256;          // B rows = n
    }

    f32x4 acc[2];
    acc[0] = f32x4{0.f, 0.f, 0.f, 0.f};
    acc[1] = f32x4{0.f, 0.f, 0.f, 0.f};

    for (int ks = 0; ks < 4; ++ks) {
      stage_g<2>(Ab, mblk, as_, ak + ks * 64, At, tid);
      stage_g<1>(Bb, nblk, bs_, ks * 64, Bt, tid);
      __syncthreads();
#pragma unroll
      for (int sk = 0; sk < 2; ++sk) {
        short8v af0 = frag(At, (wr >> 4) + 0, sk, lane);
        short8v af1 = frag(At, (wr >> 4) + 1, sk, lane);
        short8v bf0 = frag(Bt, (wc >> 4), sk, lane);
        acc[0] = __builtin_amdgcn_mfma_f32_16x16x32_bf16(af0, bf0, acc[0], 0, 0, 0);
        acc[1] = __builtin_amdgcn_mfma_f32_16x16x32_bf16(af1, bf0, acc[1], 0, 0, 0);
      }
      __syncthreads();
    }

    if (!isR) {
      int col = nblk + wc + (lane & 15);
      float c2 = c2m[col], bl = b_lin[col];
#pragma unroll
      for (int rf = 0; rf < 2; ++rf) {
        int rbase = mblk + wr + rf * 16 + ((lane >> 4) << 2);
#pragma unroll
        for (int q = 0; q < 4; ++q)
          L2p[(size_t)b * BS + (size_t)(rbase + q) * 256 + col] =
              c2 * (acc[rf][q] + bl);
      }
    } else {
      int col = nblk + wc + (lane & 15);
#pragma unroll
      for (int rf = 0; rf < 2; ++rf) {
        int rbase = mblk + wr + rf * 16 + ((lane >> 4) << 2);
#pragma unroll
        for (int q = 0; q < 4; ++q) {
          int row = rbase + q;
          R2t[(size_t)b * BS + (size_t)row * 256 + col] = c2m[row] * acc[rf][q];
        }
      }
    }
  }
  grid.sync();

  // ---------------- Stage 2: scores + softmax ----------------
  {
    float4* Lq = (float4*)smem_raw;           // 256 float4
    float* sS = (float*)(smem_raw + 4096);    // 256 f
    const int b = bk >> 6, i0 = (bk & 63) * 4;
    const int j = tid;
    const float* Lb = L2p + (size_t)b * BS + (size_t)i0 * 256;
    Lq[j] = make_float4(Lb[j], Lb[256 + j], Lb[512 + j], Lb[768 + j]);
    sS[j] = sgn[j];
    __syncthreads();

    const float* Rb = R2t + (size_t)b * BS;
    float e0 = 0.f, e1 = 0.f, e2 = 0.f, e3 = 0.f, srj = 0.f;
#pragma unroll 8
    for (int d = 0; d < 256; ++d) {
      float rv = Rb[d * 256 + j];
      float4 lq = Lq[d];
      float sd = sS[d];
      srj = fmaf(sd, rv, srj);
      float t0 = lq.x + rv, t1 = lq.y + rv, t2 = lq.z + rv, t3 = lq.w + rv;
      e0 = fmaf(sd, fabsf(t0), e0);
      e1 = fmaf(sd, fabsf(t1), e1);
      e2 = fmaf(sd, fabsf(t2), e2);
      e3 = fmaf(sd, fabsf(t3), e3);
    }
    float ev[4] = {e0, e1, e2, e3};
    const float sbase = 1.5f * srj;
    const float NEG_INF = -__builtin_inff();
#pragma unroll
    for (int ii = 0; ii < 4; ++ii) {
      int row = i0 + ii;
      ev[ii] += sbase + bias[row * 256 + j];
      ev[ii] = (adj[(size_t)b * BS + (size_t)row * 256 + j] == 0) ? NEG_INF
                                                                  : ev[ii];
    }
#pragma unroll
    for (int ii = 0; ii < 4; ++ii) {
      float v = ev[ii];
#pragma unroll
      for (int off = 32; off >= 1; off >>= 1)
        v = fmaxf(v, __shfl_xor(v, off, 64));
      if (lane == 0) redm[wid][ii] = v;
    }
    __syncthreads();
    float p4[4];
#pragma unroll
    for (int ii = 0; ii < 4; ++ii) {
      float m = fmaxf(fmaxf(redm[0][ii], redm[1][ii]),
                      fmaxf(redm[2][ii], redm[3][ii]));
      p4[ii] = (m == NEG_INF) ? 1.f : __expf(ev[ii] - m);
    }
#pragma unroll
    for (int ii = 0; ii < 4; ++ii) {
      float v = p4[ii];
#pragma unroll
      for (int off = 32; off >= 1; off >>= 1) v += __shfl_xor(v, off, 64);
      if (lane == 0) reds[wid][ii] = v;
    }
    __syncthreads();
#pragma unroll
    for (int ii = 0; ii < 4; ++ii) {
      float ssum = reds[0][ii] + reds[1][ii] + reds[2][ii] + reds[3][ii];
      attnh[(size_t)b * BS + (size_t)(i0 + ii) * 256 + j] =
          f2bf(p4[ii] / ssum);
    }
  }
  grid.sync();

  // ---------------- Stage 3: out = sigmoid(x.attn^T) + x ----------------
  {
    u16* At = (u16*)smem_raw;            // 32x64 (x rows f, bf16)
    u16* Bt = (u16*)(smem_raw + 4096);   // 32x64 (attn rows i)
    const int b = bk >> 6, tt = bk & 63;
    const int mblk = (tt >> 3) * 32, nblk = (tt & 7) * 32;
    const int wr = (wid >> 1) * 16, wc = (wid & 1) * 16;
    const float* Ax = x + (size_t)b * BS;
    const u16* Bb = attnh + (size_t)b * BS;

    f32x4 acc = f32x4{0.f, 0.f, 0.f, 0.f};
    for (int ks = 0; ks < 4; ++ks) {
      stage_g<1>(Bb, nblk, 256, ks * 64, Bt, tid);
      {
        int r = tid >> 3, c = tid & 7;
        const float* src = Ax + (size_t)(mblk + r) * 256 + ks * 64 + c * 8;
        float4 v0 = *(const float4*)src;
        float4 v1 = *(const float4*)(src + 4);
        u16 o[8] = {f2bf(v0.x), f2bf(v0.y), f2bf(v0.z), f2bf(v0.w),
                    f2bf(v1.x), f2bf(v1.y), f2bf(v1.z), f2bf(v1.w)};
        int cs = c ^ (r & 7);
        *(short8v*)(At + r * 64 + cs * 8) = *(const short8v*)o;
      }
      __syncthreads();
#pragma unroll
      for (int sk = 0; sk < 2; ++sk) {
        short8v af = frag(At, wr >> 4, sk, lane);
        short8v bf0 = frag(Bt, wc >> 4, sk, lane);
        acc = __builtin_amdgcn_mfma_f32_16x16x32_bf16(af, bf0, acc, 0, 0, 0);
      }
      __syncthreads();
    }

    int col = nblk + wc + (lane & 15);
    int rbase = mblk + wr + ((lane >> 4) << 2);
#pragma unroll
    for (int q = 0; q < 4; ++q) {
      size_t idx = (size_t)b * BS + (size_t)(rbase + q) * 256 + col;
      float sg = 1.f / (1.f + __expf(-acc[q]));
      out[idx] = sg + x[idx];
    }
  }
}

extern "C" void kernel_launch(void* const* d_in, const int* in_sizes, int n_in,
                              void* d_out, int out_size, void* d_ws,
                              size_t ws_size, hipStream_t stream) {
  const float* x = (const float*)d_in[0];
  const int* adj = (const int*)d_in[1];
  const float* W = (const float*)d_in[2];
  const float* b_lin = (const float*)d_in[3];
  const float* a = (const float*)d_in[4];
  const float* bias = (const float*)d_in[5];
  float* out = (float*)d_out;

  float* f = (float*)d_ws;
  float* L2p = f;                  // 524288 f
  float* R2t = L2p + BB * BS;      // 524288 f
  float* p = R2t + BB * BS;
  u16* xt = (u16*)p;               // 524288 u16
  p += 262144;
  u16* Wh = (u16*)p;               // 131072 u16
  p += 65536;
  u16* attnh = (u16*)p;            // 524288 u16
  p += 262144;
  float* c2m = p;                  // 256
  float* sgn = c2m + 256;          // 256

  void* args[] = {&x,   &adj, &W,  &b_lin, &a,     &bias, &out,
                  &L2p, &R2t, &xt, &Wh,    &attnh, &c2m,  &sgn};
  hipLaunchCooperativeKernel((const void*)gat_mega, dim3(512), dim3(256), args,
                             0, stream);
}

// Round 6
// 28.684 us; speedup vs baseline: 7.3368x; 7.3368x over previous
//
#include <hip/hip_runtime.h>
#include <hip/hip_bf16.h>
#include <math.h>

#define BB 8
#define BS 65536  // 256*256

typedef __attribute__((ext_vector_type(8))) short short8v;
typedef __attribute__((ext_vector_type(4))) float f32x4;
typedef unsigned short u16;
typedef __attribute__((address_space(1))) const void gv_t;
typedef __attribute__((address_space(3))) void lv_t;

__device__ __forceinline__ u16 f2bf(float v) {
  __hip_bfloat16 h = __float2bfloat16(v);
  return *reinterpret_cast<u16*>(&h);
}

// MFMA LDS tiles: [32 rows][64 k] bf16 (4 KiB), row = 128 B = 8 chunks x 16 B.
// XOR swizzle cs = c ^ (r&7), applied identically on write and read (#21).
__device__ __forceinline__ short8v frag(const u16* lds, int rb, int sk,
                                        int lane) {
  int r = rb * 16 + (lane & 15);
  int c = sk * 4 + (lane >> 4);
  int cs = c ^ (r & 7);
  return *(const short8v*)(lds + r * 64 + cs * 8);
}

// gload_lds staging for a 32x64 bf16 tile: source pre-swizzled, LDS linear.
__device__ __forceinline__ void stage_g32(const u16* __restrict__ g, int row0,
                                          int stride, int k0, u16* lds,
                                          int tid) {
  int r = tid >> 3, c = tid & 7;
  int cs = c ^ (r & 7);
  const u16* src = g + (size_t)(row0 + r) * stride + k0 + cs * 8;
  u16* dst = lds + (size_t)(tid & ~63) * 8;  // wave-uniform base
  __builtin_amdgcn_global_load_lds((gv_t*)src, (lv_t*)dst, 16, 0, 0);
}

// ---------------------------------------------------------------------------
// D1: merged projection GEMMs, batch-affine (b = blockIdx & 7 -> XCD b).
//  L2p[b][n][dd] = |0.4a[dd]|*( sum_f x[f,n] W[dd,f]      + b_lin[dd] )
//  R2t[b][dd][n] = |0.4a[dd]|*( sum_f x[f,n] W[dd,256+f] )
// 512 blocks x 256 thr; block = (b, n0 = (t>>3)*32, dd0 = (t&7)*32).
// Per ks(4): stage x[64f][32n] f32 -> LDS (coalesced); transpose+cvt -> XT
// bf16 swizzled; W1/W2 rows reg-staged f32->bf16 swizzled. 4 waves, each
// computes one 16x16 quadrant of BOTH acc_L = XT.W1^T and acc_R = W2.XT^T.
// ---------------------------------------------------------------------------
__global__ __launch_bounds__(256) void d1_proj(
    const float* __restrict__ x, const float* __restrict__ W,
    const float* __restrict__ b_lin, const float* __restrict__ a,
    float* __restrict__ L2p, float* __restrict__ R2t) {
  __shared__ float xf[64][33];
  __shared__ u16 XT[32 * 64], B1[32 * 64], B2[32 * 64];
  const int bk = blockIdx.x, tid = threadIdx.x;
  const int b = bk & 7, t = bk >> 3;
  const int n0 = (t >> 3) * 32, dd0 = (t & 7) * 32;
  const int lane = tid & 63, wid = tid >> 6;
  const int nh = wid >> 1, dh = wid & 1;
  const float* xb = x + (size_t)b * BS;

  const int r8 = tid >> 5, c32 = tid & 31;   // x-tile staging coords
  const int rw = tid >> 3, cw = tid & 7;     // W / XT staging coords

  f32x4 accL = f32x4{0.f, 0.f, 0.f, 0.f};
  f32x4 accR = f32x4{0.f, 0.f, 0.f, 0.f};

  for (int ks = 0; ks < 4; ++ks) {
    // P1: global loads -> regs, x -> LDS f32
    float xr[8];
#pragma unroll
    for (int it = 0; it < 8; ++it)
      xr[it] = xb[(size_t)(ks * 64 + it * 8 + r8) * 256 + n0 + c32];
    float4 wa0 = *(const float4*)&W[(size_t)(dd0 + rw) * 512 + ks * 64 + cw * 8];
    float4 wa1 = *(const float4*)&W[(size_t)(dd0 + rw) * 512 + ks * 64 + cw * 8 + 4];
    float4 wb0 = *(const float4*)&W[(size_t)(dd0 + rw) * 512 + 256 + ks * 64 + cw * 8];
    float4 wb1 = *(const float4*)&W[(size_t)(dd0 + rw) * 512 + 256 + ks * 64 + cw * 8 + 4];
#pragma unroll
    for (int it = 0; it < 8; ++it) xf[it * 8 + r8][c32] = xr[it];
    __syncthreads();
    // P2: XT (transposed x, bf16, swizzled) + B1/B2 (W rows, bf16, swizzled)
    {
      u16 o[8];
#pragma unroll
      for (int e = 0; e < 8; ++e) o[e] = f2bf(xf[cw * 8 + e][rw]);
      *(short8v*)&XT[rw * 64 + ((cw ^ (rw & 7)) * 8)] = *(const short8v*)o;
      u16 o1[8] = {f2bf(wa0.x), f2bf(wa0.y), f2bf(wa0.z), f2bf(wa0.w),
                   f2bf(wa1.x), f2bf(wa1.y), f2bf(wa1.z), f2bf(wa1.w)};
      *(short8v*)&B1[rw * 64 + ((cw ^ (rw & 7)) * 8)] = *(const short8v*)o1;
      u16 o2[8] = {f2bf(wb0.x), f2bf(wb0.y), f2bf(wb0.z), f2bf(wb0.w),
                   f2bf(wb1.x), f2bf(wb1.y), f2bf(wb1.z), f2bf(wb1.w)};
      *(short8v*)&B2[rw * 64 + ((cw ^ (rw & 7)) * 8)] = *(const short8v*)o2;
    }
    __syncthreads();
    // P3: MFMA
#pragma unroll
    for (int sk = 0; sk < 2; ++sk) {
      short8v xa = frag(XT, nh, sk, lane);
      short8v w1 = frag(B1, dh, sk, lane);
      short8v w2 = frag(B2, dh, sk, lane);
      accL = __builtin_amdgcn_mfma_f32_16x16x32_bf16(xa, w1, accL, 0, 0, 0);
      accR = __builtin_amdgcn_mfma_f32_16x16x32_bf16(w2, xa, accR, 0, 0, 0);
    }
    // next P1's xf writes are fenced by the P1->P2 __syncthreads
  }

  // epilogue: L2p[n][dd]
  {
    int ddc = dd0 + dh * 16 + (lane & 15);
    float c2 = fabsf(0.4f * a[ddc]);
    float bl = b_lin[ddc];
    int nr = n0 + nh * 16 + ((lane >> 4) << 2);
#pragma unroll
    for (int q = 0; q < 4; ++q)
      L2p[(size_t)b * BS + (size_t)(nr + q) * 256 + ddc] = c2 * (accL[q] + bl);
  }
  // epilogue: R2t[dd][n]
  {
    int nc = n0 + nh * 16 + (lane & 15);
    int ddr = dd0 + dh * 16 + ((lane >> 4) << 2);
#pragma unroll
    for (int q = 0; q < 4; ++q) {
      float c2 = fabsf(0.4f * a[ddr + q]);
      R2t[(size_t)b * BS + (size_t)(ddr + q) * 256 + nc] = c2 * accR[q];
    }
  }
}

// ---------------------------------------------------------------------------
// D2: scores + softmax, batch-affine. 256 blocks x 512 thr (1 block/CU).
// e[i,j] = 1.5*sum_d sgn*R2t[d,j] + bias[i,j] + sum_d sgn[d]*|L2p[i,d]+R2t[d,j]|
// mask, softmax over j -> attnh bf16 [i][j] (k-contiguous for D3).
// block = (b = bk&7, i0 = (bk>>3)*8); thread = (j = t&255, ih = t>>8).
// ---------------------------------------------------------------------------
__global__ __launch_bounds__(512) void d2_scores(
    const float* __restrict__ R2t, const float* __restrict__ L2p,
    const float* __restrict__ a, const int* __restrict__ adj,
    const float* __restrict__ bias, u16* __restrict__ attnh) {
  __shared__ float4 Lq[2][256];
  __shared__ float sS[256];
  __shared__ float redm[8][4], reds[8][4];
  const int t = threadIdx.x, j = t & 255, ih = t >> 8;
  const int bk = blockIdx.x, b = bk & 7, i0 = (bk >> 3) * 8;
  {
    const float* Lb = L2p + (size_t)b * BS + (size_t)(i0 + ih * 4) * 256;
    Lq[ih][j] = make_float4(Lb[j], Lb[256 + j], Lb[512 + j], Lb[768 + j]);
    if (t < 256) sS[t] = (a[t] >= 0.f) ? 1.f : -1.f;
  }
  __syncthreads();

  const float* Rb = R2t + (size_t)b * BS;
  float e0 = 0.f, e1 = 0.f, e2 = 0.f, e3 = 0.f, srj = 0.f;
#pragma unroll 16
  for (int d = 0; d < 256; ++d) {
    float rv = Rb[d * 256 + j];
    float4 lq = Lq[ih][d];
    float sd = sS[d];
    srj = fmaf(sd, rv, srj);
    float t0 = lq.x + rv, t1 = lq.y + rv, t2 = lq.z + rv, t3 = lq.w + rv;
    e0 = fmaf(sd, fabsf(t0), e0);
    e1 = fmaf(sd, fabsf(t1), e1);
    e2 = fmaf(sd, fabsf(t2), e2);
    e3 = fmaf(sd, fabsf(t3), e3);
  }
  float ev[4] = {e0, e1, e2, e3};
  const float sbase = 1.5f * srj;
  const float NEG_INF = -__builtin_inff();
#pragma unroll
  for (int ii = 0; ii < 4; ++ii) {
    int row = i0 + ih * 4 + ii;
    ev[ii] += sbase + bias[row * 256 + j];
    ev[ii] = (adj[(size_t)b * BS + (size_t)row * 256 + j] == 0) ? NEG_INF
                                                                : ev[ii];
  }
  const int wid = t >> 6, lane = t & 63, wb = ih * 4;
#pragma unroll
  for (int ii = 0; ii < 4; ++ii) {
    float v = ev[ii];
#pragma unroll
    for (int off = 32; off >= 1; off >>= 1) v = fmaxf(v, __shfl_xor(v, off, 64));
    if (lane == 0) redm[wid][ii] = v;
  }
  __syncthreads();
  float p4[4];
#pragma unroll
  for (int ii = 0; ii < 4; ++ii) {
    float m = fmaxf(fmaxf(redm[wb][ii], redm[wb + 1][ii]),
                    fmaxf(redm[wb + 2][ii], redm[wb + 3][ii]));
    p4[ii] = (m == NEG_INF) ? 1.f : __expf(ev[ii] - m);
  }
#pragma unroll
  for (int ii = 0; ii < 4; ++ii) {
    float v = p4[ii];
#pragma unroll
    for (int off = 32; off >= 1; off >>= 1) v += __shfl_xor(v, off, 64);
    if (lane == 0) reds[wid][ii] = v;
  }
  __syncthreads();
#pragma unroll
  for (int ii = 0; ii < 4; ++ii) {
    float ssum = reds[wb][ii] + reds[wb + 1][ii] + reds[wb + 2][ii] +
                 reds[wb + 3][ii];
    attnh[(size_t)b * BS + (size_t)(i0 + ih * 4 + ii) * 256 + j] =
        f2bf(p4[ii] / ssum);
  }
}

// ---------------------------------------------------------------------------
// D3: out[b][f][i] = sigmoid( sum_j x[f][j]*attn[i][j] ) + x[b][f][i]
// batch-affine, 512 blocks x 256 thr; block = (b, f0 = (t>>3)*32,
// i0 = (t&7)*32). A = x rows f (reg-staged f32->bf16, swizzled ds_write);
// B = attnh rows i (gload_lds, pre-swizzled source). 4 waves, 1 quad each.
// ---------------------------------------------------------------------------
__global__ __launch_bounds__(256) void d3_out(const u16* __restrict__ attnh,
                                              const float* __restrict__ x,
                                              float* __restrict__ out) {
  __shared__ u16 At[32 * 64], Bt[32 * 64];
  const int bk = blockIdx.x, tid = threadIdx.x;
  const int b = bk & 7, t = bk >> 3;
  const int f0 = (t >> 3) * 32, i0 = (t & 7) * 32;
  const int lane = tid & 63, wid = tid >> 6;
  const int fh = wid >> 1, ih2 = wid & 1;
  const float* Ax = x + (size_t)b * BS;
  const u16* Bb = attnh + (size_t)b * BS;
  const int rw = tid >> 3, cw = tid & 7;

  f32x4 acc = f32x4{0.f, 0.f, 0.f, 0.f};
  for (int ks = 0; ks < 4; ++ks) {
    stage_g32(Bb, i0, 256, ks * 64, Bt, tid);
    {
      const float* src = Ax + (size_t)(f0 + rw) * 256 + ks * 64 + cw * 8;
      float4 v0 = *(const float4*)src;
      float4 v1 = *(const float4*)(src + 4);
      u16 o[8] = {f2bf(v0.x), f2bf(v0.y), f2bf(v0.z), f2bf(v0.w),
                  f2bf(v1.x), f2bf(v1.y), f2bf(v1.z), f2bf(v1.w)};
      *(short8v*)&At[rw * 64 + ((cw ^ (rw & 7)) * 8)] = *(const short8v*)o;
    }
    __syncthreads();
#pragma unroll
    for (int sk = 0; sk < 2; ++sk) {
      short8v af = frag(At, fh, sk, lane);
      short8v bf = frag(Bt, ih2, sk, lane);
      acc = __builtin_amdgcn_mfma_f32_16x16x32_bf16(af, bf, acc, 0, 0, 0);
    }
    __syncthreads();
  }

  int col = i0 + ih2 * 16 + (lane & 15);
  int rbase = f0 + fh * 16 + ((lane >> 4) << 2);
#pragma unroll
  for (int q = 0; q < 4; ++q) {
    size_t idx = (size_t)b * BS + (size_t)(rbase + q) * 256 + col;
    float sg = 1.f / (1.f + __expf(-acc[q]));
    out[idx] = sg + x[idx];
  }
}

extern "C" void kernel_launch(void* const* d_in, const int* in_sizes, int n_in,
                              void* d_out, int out_size, void* d_ws,
                              size_t ws_size, hipStream_t stream) {
  const float* x = (const float*)d_in[0];
  const int* adj = (const int*)d_in[1];
  const float* W = (const float*)d_in[2];
  const float* b_lin = (const float*)d_in[3];
  const float* a = (const float*)d_in[4];
  const float* bias = (const float*)d_in[5];
  float* out = (float*)d_out;

  float* L2p = (float*)d_ws;       // 524288 f
  float* R2t = L2p + BB * BS;      // 524288 f
  u16* attnh = (u16*)(R2t + BB * BS);  // 524288 u16

  d1_proj<<<512, 256, 0, stream>>>(x, W, b_lin, a, L2p, R2t);
  d2_scores<<<256, 512, 0, stream>>>(R2t, L2p, a, adj, bias, attnh);
  d3_out<<<512, 256, 0, stream>>>(attnh, x, out);
}